// Round 3
// baseline (1324.595 us; speedup 1.0000x reference)
//
#include <hip/hip_runtime.h>

typedef _Float16 f16;
typedef _Float16 f16x8 __attribute__((ext_vector_type(8)));
typedef _Float16 f16x4 __attribute__((ext_vector_type(4)));
typedef float    f32x16 __attribute__((ext_vector_type(16)));

#define GLDS(gp, lp) __builtin_amdgcn_global_load_lds( \
    (const __attribute__((address_space(1))) void*)(gp), \
    (__attribute__((address_space(3))) void*)(lp), 16, 0, 0)

// ---------------------------------------------------------------------------
// 256x256 tile, BK=64, 512 threads (8 waves 2x4, 128x64 per wave), 8-phase
// K-loop.  A: global_load_lds double-buffer (XOR-swizzled).  B: loaded
// DIRECTLY global->regs per wave (B-panels are L2/L3-resident; removes all
// B ds_reads + B LDS writes from the barrier-locked LDS window).
// b-regs single-buffered: reloaded at P3/P7 after their last MFMA use
// (1-phase lead, covered by L2/L3 latency).  Counted vmcnt keeps the A
// pipeline 3 half-tiles deep; never drains to 0 in the main loop.
// ---------------------------------------------------------------------------
template<typename OUT_T, bool BIAS, bool RELU>
__global__ __launch_bounds__(512, 2)
void gemm_bt2(const f16* __restrict__ A, const f16* __restrict__ Bm,
              OUT_T* __restrict__ C, const float* __restrict__ bias,
              int M, int N, int K, long sA, long sB, long sC)
{
    constexpr int TSZ = 256 * 64;          // f16 elements per A tile buffer
    __shared__ alignas(16) f16 As[2 * TSZ];   // 64 KiB (A only)

    int bx = blockIdx.x, by = blockIdx.y;
    {   // XCD-locality remap (gy % 8 == 0 for all uses)
        const int gx = gridDim.x;
        const int l = by * gx + bx;
        const int W = gx * 8;
        const int ygrp = l / W;
        const int rem = l - ygrp * W;
        bx = rem >> 3;
        by = ygrp * 8 + (rem & 7);
    }
    const int z = blockIdx.z;
    A  += (long)z * sA;
    Bm += (long)z * sB;
    C  += (long)z * sC;

    const int tid  = threadIdx.x;
    const int wid  = tid >> 6;
    const int lane = tid & 63;
    const int lr = lane & 31;
    const int lh = lane >> 5;
    const int m0 = by * 256;
    const int n0 = bx * 256;
    const int wm = (wid >> 2) * 128;       // wave row: 0 or 128
    const int wn = (wid & 3) * 64;         // wave col: 0,64,128,192

    // A staging: one GLDS call covers 64 rows (8 rows/wave, 8 x 16B slots).
    // LDS row r slot s holds source k-segment (s ^ (r&7))  [XOR swizzle]
    const int sr = tid >> 3;
    const int sg = ((tid & 7) ^ (sr & 7)) * 8;
    const f16* agS = A + (long)(m0 + sr) * K + sg;
    f16* aD = As + wid * (8 * 64);                   // wave-uniform LDS base

    // A fragment read: k-segment g = 2*ks + lh at slot g ^ (row&7)
    const int s7  = lr & 7;
    const int xs0 = ((0 + lh) ^ s7) * 8;
    const int xs1 = ((2 + lh) ^ s7) * 8;
    const int xs2 = ((4 + lh) ^ s7) * 8;
    const int xs3 = ((6 + lh) ^ s7) * 8;
    const f16* aR = As + (wm + lr) * 64;

    // B fragment global pointers: frag(grp,ks) = Bm[n0+wn+grp*32+lr][kt+ks*16+lh*8]
    const f16* bgl0 = Bm + (long)(n0 + wn + lr) * K + lh * 8;
    const f16* bgl1 = bgl0 + (long)32 * K;

    f32x16 acc[4][2];
#pragma unroll
    for (int mi = 0; mi < 4; ++mi)
#pragma unroll
        for (int ni = 0; ni < 2; ++ni)
#pragma unroll
            for (int r = 0; r < 16; ++r) acc[mi][ni][r] = 0.f;

    f16x8 bb0, bb1, bb2, bb3, bb4, bb5, bb6, bb7;

    const int NT = K >> 6;

#define GAc(buf, R0, kt) GLDS(agS + (long)(R0) * K + (kt), aD + (buf) * TSZ + (R0) * 64)
// B reload: pinned after the MFMA cluster (sched_barrier) so the loads can't
// hoist above the last use of the previous values.
#define BLD(kt) __builtin_amdgcn_sched_barrier(0); \
    bb0 = *(const f16x8*)(bgl0 + (kt));      bb1 = *(const f16x8*)(bgl0 + (kt) + 16); \
    bb2 = *(const f16x8*)(bgl0 + (kt) + 32); bb3 = *(const f16x8*)(bgl0 + (kt) + 48); \
    bb4 = *(const f16x8*)(bgl1 + (kt));      bb5 = *(const f16x8*)(bgl1 + (kt) + 16); \
    bb6 = *(const f16x8*)(bgl1 + (kt) + 32); bb7 = *(const f16x8*)(bgl1 + (kt) + 48);

    // prologue: B(tile0) -> regs; A tile0 full + tile1 head -> LDS
    BLD(0)
    GAc(0,   0, 0);  GAc(0,  64, 0);  GAc(0, 128, 0);  GAc(0, 192, 0);
    GAc(1,   0, 64); GAc(1, 128, 64);
    asm volatile("s_waitcnt vmcnt(2)" ::: "memory");   // bb + A0 landed
    __builtin_amdgcn_s_barrier();

#define MFMA8(mi) \
    acc[mi][0] = __builtin_amdgcn_mfma_f32_32x32x16_f16(af0, bb0, acc[mi][0], 0, 0, 0); \
    acc[mi][1] = __builtin_amdgcn_mfma_f32_32x32x16_f16(af0, bb4, acc[mi][1], 0, 0, 0); \
    acc[mi][0] = __builtin_amdgcn_mfma_f32_32x32x16_f16(af1, bb1, acc[mi][0], 0, 0, 0); \
    acc[mi][1] = __builtin_amdgcn_mfma_f32_32x32x16_f16(af1, bb5, acc[mi][1], 0, 0, 0); \
    acc[mi][0] = __builtin_amdgcn_mfma_f32_32x32x16_f16(af2, bb2, acc[mi][0], 0, 0, 0); \
    acc[mi][1] = __builtin_amdgcn_mfma_f32_32x32x16_f16(af2, bb6, acc[mi][1], 0, 0, 0); \
    acc[mi][0] = __builtin_amdgcn_mfma_f32_32x32x16_f16(af3, bb3, acc[mi][0], 0, 0, 0); \
    acc[mi][1] = __builtin_amdgcn_mfma_f32_32x32x16_f16(af3, bb7, acc[mi][1], 0, 0, 0);

// Phase: 4 A ds_reads | GLDS issues | barrier | lgkm0 | 8 MFMA | [B reload]
//        | [vmcnt gate] | barrier
#define PH(buf, mi, VW, BL, ...) { \
    f16x8 af0 = *(const f16x8*)(aR + (buf) * TSZ + (mi) * 2048 + xs0); \
    f16x8 af1 = *(const f16x8*)(aR + (buf) * TSZ + (mi) * 2048 + xs1); \
    f16x8 af2 = *(const f16x8*)(aR + (buf) * TSZ + (mi) * 2048 + xs2); \
    f16x8 af3 = *(const f16x8*)(aR + (buf) * TSZ + (mi) * 2048 + xs3); \
    __VA_ARGS__ \
    __builtin_amdgcn_s_barrier(); \
    asm volatile("s_waitcnt lgkmcnt(0)" ::: "memory"); \
    __builtin_amdgcn_s_setprio(1); \
    MFMA8(mi) \
    __builtin_amdgcn_s_setprio(0); \
    BL \
    if (VW) { asm volatile("s_waitcnt vmcnt(10)" ::: "memory"); } \
    __builtin_amdgcn_s_barrier(); \
}

    for (int i = 0; i < NT / 2; ++i) {
        const long k1 = (long)(2 * i + 1) << 6;                           // tile t+1
        const long kA = (2 * i + 2 < NT) ? ((long)(2 * i + 2) << 6) : 0;  // tile t+2
        const long kB = (2 * i + 3 < NT) ? ((long)(2 * i + 3) << 6) : 0;  // tile t+3
        PH(0, 0, 0, ,        GAc(1,  64, k1); GAc(1, 192, k1);)
        PH(0, 1, 0, ,        )
        PH(0, 2, 0, ,        )
        PH(0, 3, 1, BLD(k1), GAc(0,   0, kA); GAc(0, 128, kA);)   // bb <- B(t+1)
        PH(1, 0, 0, ,        GAc(0,  64, kA); GAc(0, 192, kA);)
        PH(1, 1, 0, ,        )
        PH(1, 2, 0, ,        )
        PH(1, 3, 1, BLD(kA), GAc(1,   0, kB); GAc(1, 128, kB);)   // bb <- B(t+2)
    }

    asm volatile("s_waitcnt vmcnt(0)" ::: "memory");    // drain before LDS dealloc

    // C/D layout (32x32): col = lane&31, row = (reg&3) + 8*(reg>>2) + 4*(lane>>5)
#pragma unroll
    for (int ni = 0; ni < 2; ++ni) {
        const int gc = n0 + wn + ni * 32 + lr;
        const float bv = BIAS ? bias[gc] : 0.0f;
#pragma unroll
        for (int mi = 0; mi < 4; ++mi) {
#pragma unroll
            for (int r = 0; r < 16; ++r) {
                const int row = (r & 3) + 8 * (r >> 2) + 4 * lh;
                const int gr = m0 + wm + mi * 32 + row;
                float v = acc[mi][ni][r] + bv;
                if (RELU) v = fmaxf(v, 0.0f);
                C[(long)gr * N + gc] = (OUT_T)v;
            }
        }
    }
#undef PH
#undef MFMA8
#undef BLD
#undef GAc
}

// ---------------------------------------------------------------------------
// 256x128 tile, BK=64, 512 threads (8 waves 4M x 2N, 64x64 per wave),
// 4-phase K-loop.  Same B-direct-from-global scheme as gemm_bt2:
//   P0(buf0,mi0): A1-fill x4 (tile t+1)
//   P1(buf0,mi1): bb <- B(t+1) after MFMA; vmcnt(8) -> A1 landed
//   P2(buf1,mi0): A0-fill x4 (tile t+2)
//   P3(buf1,mi1): bb <- B(t+2) after MFMA; vmcnt(8) -> A0 landed
// ---------------------------------------------------------------------------
template<typename OUT_T, bool BIAS, bool RELU>
__global__ __launch_bounds__(512, 2)
void gemm_bt3(const f16* __restrict__ A, const f16* __restrict__ Bm,
              OUT_T* __restrict__ C, const float* __restrict__ bias,
              int M, int N, int K, long sA, long sB, long sC)
{
    constexpr int TSA = 256 * 64;
    __shared__ alignas(16) f16 As[2 * TSA];   // 64 KiB (A only)

    int bx = blockIdx.x, by = blockIdx.y;
    {   // XCD-locality remap (gy % 8 == 0 for all uses)
        const int gx = gridDim.x;
        const int l = by * gx + bx;
        const int W = gx * 8;
        const int ygrp = l / W;
        const int rem = l - ygrp * W;
        bx = rem >> 3;
        by = ygrp * 8 + (rem & 7);
    }
    const int z = blockIdx.z;
    A  += (long)z * sA;
    Bm += (long)z * sB;
    C  += (long)z * sC;

    const int tid  = threadIdx.x;
    const int wid  = tid >> 6;
    const int lane = tid & 63;
    const int lr = lane & 31;
    const int lh = lane >> 5;
    const int m0 = by * 256;
    const int n0 = bx * 128;
    const int wm = (wid >> 1) * 64;        // 4 M-waves: 0,64,128,192
    const int wn = (wid & 1) * 64;         // 2 N-waves: 0,64

    const int sr = tid >> 3;
    const int sg = ((tid & 7) ^ (sr & 7)) * 8;
    const f16* agS = A + (long)(m0 + sr) * K + sg;
    f16* aD = As + wid * (8 * 64);

    const int s7  = lr & 7;
    const int xs0 = ((0 + lh) ^ s7) * 8;
    const int xs1 = ((2 + lh) ^ s7) * 8;
    const int xs2 = ((4 + lh) ^ s7) * 8;
    const int xs3 = ((6 + lh) ^ s7) * 8;
    const f16* aR = As + (wm + lr) * 64;

    const f16* bgl0 = Bm + (long)(n0 + wn + lr) * K + lh * 8;
    const f16* bgl1 = bgl0 + (long)32 * K;

    f32x16 acc[2][2];
#pragma unroll
    for (int mi = 0; mi < 2; ++mi)
#pragma unroll
        for (int ni = 0; ni < 2; ++ni)
#pragma unroll
            for (int r = 0; r < 16; ++r) acc[mi][ni][r] = 0.f;

    f16x8 bb0, bb1, bb2, bb3, bb4, bb5, bb6, bb7;

    const int NT = K >> 6;

#define GA3(buf, R0, kt) GLDS(agS + (long)(R0) * K + (kt), aD + (buf) * TSA + (R0) * 64)
#define BLD3(kt) __builtin_amdgcn_sched_barrier(0); \
    bb0 = *(const f16x8*)(bgl0 + (kt));      bb1 = *(const f16x8*)(bgl0 + (kt) + 16); \
    bb2 = *(const f16x8*)(bgl0 + (kt) + 32); bb3 = *(const f16x8*)(bgl0 + (kt) + 48); \
    bb4 = *(const f16x8*)(bgl1 + (kt));      bb5 = *(const f16x8*)(bgl1 + (kt) + 16); \
    bb6 = *(const f16x8*)(bgl1 + (kt) + 32); bb7 = *(const f16x8*)(bgl1 + (kt) + 48);

    // prologue: B(tile0) -> regs; A tile0 -> LDS buf0
    BLD3(0)
    GA3(0,   0, 0);  GA3(0,  64, 0);  GA3(0, 128, 0);  GA3(0, 192, 0);
    asm volatile("s_waitcnt vmcnt(0)" ::: "memory");
    __builtin_amdgcn_s_barrier();

#define MFMA8_3(mi) \
    acc[mi][0] = __builtin_amdgcn_mfma_f32_32x32x16_f16(af0, bb0, acc[mi][0], 0, 0, 0); \
    acc[mi][1] = __builtin_amdgcn_mfma_f32_32x32x16_f16(af0, bb4, acc[mi][1], 0, 0, 0); \
    acc[mi][0] = __builtin_amdgcn_mfma_f32_32x32x16_f16(af1, bb1, acc[mi][0], 0, 0, 0); \
    acc[mi][1] = __builtin_amdgcn_mfma_f32_32x32x16_f16(af1, bb5, acc[mi][1], 0, 0, 0); \
    acc[mi][0] = __builtin_amdgcn_mfma_f32_32x32x16_f16(af2, bb2, acc[mi][0], 0, 0, 0); \
    acc[mi][1] = __builtin_amdgcn_mfma_f32_32x32x16_f16(af2, bb6, acc[mi][1], 0, 0, 0); \
    acc[mi][0] = __builtin_amdgcn_mfma_f32_32x32x16_f16(af3, bb3, acc[mi][0], 0, 0, 0); \
    acc[mi][1] = __builtin_amdgcn_mfma_f32_32x32x16_f16(af3, bb7, acc[mi][1], 0, 0, 0);

#define PH3(buf, mi, VW, BL, ...) { \
    f16x8 af0 = *(const f16x8*)(aR + (buf) * TSA + (mi) * 2048 + xs0); \
    f16x8 af1 = *(const f16x8*)(aR + (buf) * TSA + (mi) * 2048 + xs1); \
    f16x8 af2 = *(const f16x8*)(aR + (buf) * TSA + (mi) * 2048 + xs2); \
    f16x8 af3 = *(const f16x8*)(aR + (buf) * TSA + (mi) * 2048 + xs3); \
    __VA_ARGS__ \
    __builtin_amdgcn_s_barrier(); \
    asm volatile("s_waitcnt lgkmcnt(0)" ::: "memory"); \
    __builtin_amdgcn_s_setprio(1); \
    MFMA8_3(mi) \
    __builtin_amdgcn_s_setprio(0); \
    BL \
    if (VW) { asm volatile("s_waitcnt vmcnt(8)" ::: "memory"); } \
    __builtin_amdgcn_s_barrier(); \
}

    for (int i = 0; i < NT / 2; ++i) {
        const long k1 = (long)(2 * i + 1) << 6;                           // tile t+1
        const long kA = (2 * i + 2 < NT) ? ((long)(2 * i + 2) << 6) : 0;  // tile t+2
        PH3(0, 0, 0, ,         GA3(1, 0, k1); GA3(1, 64, k1); GA3(1, 128, k1); GA3(1, 192, k1);)
        PH3(0, 1, 1, BLD3(k1), )                                  // bb <- B(t+1)
        PH3(1, 0, 0, ,         GA3(0, 0, kA); GA3(0, 64, kA); GA3(0, 128, kA); GA3(0, 192, kA);)
        PH3(1, 1, 1, BLD3(kA), )                                  // bb <- B(t+2)
    }

    asm volatile("s_waitcnt vmcnt(0)" ::: "memory");

    // C/D layout (32x32): col = lane&31, row = (reg&3) + 8*(reg>>2) + 4*(lane>>5)
#pragma unroll
    for (int ni = 0; ni < 2; ++ni) {
        const int gc = n0 + wn + ni * 32 + lr;
        const float bv = BIAS ? bias[gc] : 0.0f;
#pragma unroll
        for (int mi = 0; mi < 2; ++mi) {
#pragma unroll
            for (int r = 0; r < 16; ++r) {
                const int row = (r & 3) + 8 * (r >> 2) + 4 * lh;
                const int gr = m0 + wm + mi * 32 + row;
                float v = acc[mi][ni][r] + bv;
                if (RELU) v = fmaxf(v, 0.0f);
                C[(long)gr * N + gc] = (OUT_T)v;
            }
        }
    }
#undef PH3
#undef MFMA8_3
#undef BLD3
#undef GA3
}

// ---------------------------------------------------------------------------
__global__ __launch_bounds__(256)
void cast_f32_f16(const float* __restrict__ X, f16* __restrict__ Y)
{
    const long i = ((long)blockIdx.x * 256 + threadIdx.x) * 8;
    float4 a = *(const float4*)(X + i);
    float4 b = *(const float4*)(X + i + 4);
    f16x8 h = {(f16)a.x, (f16)a.y, (f16)a.z, (f16)a.w,
               (f16)b.x, (f16)b.y, (f16)b.z, (f16)b.w};
    *(f16x8*)(Y + i) = h;
}

// proj_q fp32 [2048 x 1024] per batch -> qB fp16 (row-major) AND qBt fp16 [1024 x 2048]
__global__ __launch_bounds__(256)
void cast_q_dual(const float* __restrict__ X, f16* __restrict__ Yrow,
                 f16* __restrict__ Ytr)
{
    __shared__ f16 t[64][72];
    const float* Xb = X + (long)blockIdx.z * (2048L * 1024);
    f16* Yrb = Yrow + (long)blockIdx.z * (2048L * 1024);
    f16* Ytb = Ytr  + (long)blockIdx.z * (1024L * 2048);
    const int r0 = blockIdx.y * 64;
    const int c0 = blockIdx.x * 64;
    const int tid = threadIdx.x;
    const int tr = tid >> 4;
    const int tc = (tid & 15) * 4;
#pragma unroll
    for (int rr = 0; rr < 64; rr += 16) {
        float4 v = *(const float4*)(Xb + (long)(r0 + tr + rr) * 1024 + c0 + tc);
        f16x4 h = {(f16)v.x, (f16)v.y, (f16)v.z, (f16)v.w};
        *(f16x4*)&t[tr + rr][tc] = h;
        *(f16x4*)(Yrb + (long)(r0 + tr + rr) * 1024 + c0 + tc) = h;
    }
    __syncthreads();
#pragma unroll
    for (int rr = 0; rr < 64; rr += 16) {
        const int orow = tr + rr;
        f16x4 o = {t[tc + 0][orow], t[tc + 1][orow], t[tc + 2][orow], t[tc + 3][orow]};
        *(f16x4*)(Ytb + (long)(c0 + orow) * 2048 + r0 + tc) = o;
    }
}

// rowwise softmax over 2048 fp32 -> fp16
__global__ __launch_bounds__(256)
void softmax_p(const float* __restrict__ S, f16* __restrict__ P)
{
    const long row = blockIdx.x;
    const float* s = S + row * 2048;
    f16* p = P + row * 2048;
    const int tid = threadIdx.x;
    const int wid = tid >> 6, lane = tid & 63;

    float4 a = *(const float4*)(s + tid * 8);
    float4 b = *(const float4*)(s + tid * 8 + 4);
    float v[8] = {a.x, a.y, a.z, a.w, b.x, b.y, b.z, b.w};

    float m = v[0];
#pragma unroll
    for (int j = 1; j < 8; ++j) m = fmaxf(m, v[j]);
#pragma unroll
    for (int off = 32; off > 0; off >>= 1) m = fmaxf(m, __shfl_xor(m, off, 64));

    __shared__ float red[8];
    if (lane == 0) red[wid] = m;
    __syncthreads();
    m = fmaxf(fmaxf(red[0], red[1]), fmaxf(red[2], red[3]));

    float sum = 0.f;
#pragma unroll
    for (int j = 0; j < 8; ++j) { v[j] = __expf(v[j] - m); sum += v[j]; }
#pragma unroll
    for (int off = 32; off > 0; off >>= 1) sum += __shfl_xor(sum, off, 64);
    if (lane == 0) red[4 + wid] = sum;
    __syncthreads();
    sum = red[4] + red[5] + red[6] + red[7];

    const float inv = 1.0f / sum;
    f16x8 h = {(f16)(v[0] * inv), (f16)(v[1] * inv), (f16)(v[2] * inv), (f16)(v[3] * inv),
               (f16)(v[4] * inv), (f16)(v[5] * inv), (f16)(v[6] * inv), (f16)(v[7] * inv)};
    *(f16x8*)(p + tid * 8) = h;
}

// ---------------------------------------------------------------------------
extern "C" void kernel_launch(void* const* d_in, const int* in_sizes, int n_in,
                              void* d_out, int out_size, void* d_ws, size_t ws_size,
                              hipStream_t stream)
{
    const float* proj_p = (const float*)d_in[0];  // [16,2048,1024]
    const float* proj_q = (const float*)d_in[1];  // [16,2048,1024]
    const float* W      = (const float*)d_in[2];  // [1024,1024]
    const float* bias   = (const float*)d_in[3];  // [1024]
    float* out = (float*)d_out;

    constexpr long Bc = 16, L = 2048, H = 1024, NB = 4;
    constexpr long nPQ = Bc * L * H;              // 33,554,432 elements

    char* ws = (char*)d_ws;
    f16*   pB  = (f16*)(ws + 0L);                 // 67,108,864 B
    f16*   qB  = (f16*)(ws + 67108864L);          // 67,108,864 B
    f16*   qBt = (f16*)(ws + 134217728L);         // 67,108,864 B  [B][H][L]
    f16*   tQ  = (f16*)(ws + 201326592L);         // 67,108,864 B
    f16*   aV  = (f16*)(ws + 268435456L);         // 67,108,864 B
    f16*   Wb  = (f16*)(ws + 335544320L);         //  2,097,152 B
    float* S   = (float*)(ws + 337641472L);       // 67,108,864 B (4 batches fp32)
    f16*   P   = (f16*)(ws + 404750336L);         // 33,554,432 B (4 batches fp16)

    cast_f32_f16<<<nPQ / (256 * 8), 256, 0, stream>>>(proj_p, pB);
    cast_f32_f16<<<(H * H) / (256 * 8), 256, 0, stream>>>(W, Wb);
    cast_q_dual<<<dim3(16, 32, 16), 256, 0, stream>>>(proj_q, qB, qBt);

    // G1: tQ[b,q,o] = qB[b,q,:] . Wb[o,:] + bias[o]   (256-tile 8-phase)
    gemm_bt2<f16, true, false><<<dim3(H / 256, (Bc * L) / 256, 1), 512, 0, stream>>>(
        qB, Wb, tQ, bias, (int)(Bc * L), (int)H, (int)H, 0, 0, 0);

    for (int c = 0; c < 4; ++c) {
        const long boff = (long)c * NB * L * H;
        // G2: S[p,q] = pB[p,:] . tQ[q,:]   (fp32 out, 256-tile 8-phase)
        gemm_bt2<float, false, false><<<dim3(L / 256, L / 256, NB), 512, 0, stream>>>(
            pB + boff, tQ + boff, S, nullptr, (int)L, (int)L, (int)H,
            L * H, L * H, L * L);
        // softmax rows -> P fp16
        softmax_p<<<NB * L, 256, 0, stream>>>(S, P);
        // G3: aV[p,h] = P[p,:] . qBt[h,:]   (256x128-tile 4-phase, K=2048)
        gemm_bt3<f16, false, false><<<dim3(H / 128, L / 256, NB), 512, 0, stream>>>(
            P, qBt + (long)c * NB * H * L, aV + boff, nullptr, (int)L, (int)H, (int)L,
            L * L, H * L, L * H);
    }

    // G4: out = relu(aV . Wb^T + bias)  (fp32 out, 256-tile 8-phase)
    gemm_bt2<float, false, true><<<dim3(H / 256, (Bc * L) / 256, 1), 512, 0, stream>>>(
        aV, Wb, out, bias, (int)(Bc * L), (int)H, (int)H, 0, 0, 0);
}

// Round 4
// 1100.461 us; speedup vs baseline: 1.2037x; 1.2037x over previous
//
#include <hip/hip_runtime.h>

typedef _Float16 f16;
typedef _Float16 f16x8 __attribute__((ext_vector_type(8)));
typedef _Float16 f16x4 __attribute__((ext_vector_type(4)));
typedef float    f32x16 __attribute__((ext_vector_type(16)));

#define GLDS(gp, lp) __builtin_amdgcn_global_load_lds( \
    (const __attribute__((address_space(1))) void*)(gp), \
    (__attribute__((address_space(3))) void*)(lp), 16, 0, 0)

// ---------------------------------------------------------------------------
// 256x256 tile, BK=64, 512 threads (8 waves 2x4, 128x64 per wave), 8-phase
// K-loop.  A: global_load_lds double-buffer (XOR-swizzled LDS, 64 KiB).
// B: DOUBLE-BUFFERED registers loaded direct global->reg (sets bx/by, one per
// K-tile parity).  Set bx dies after P3 of tile t -> reloaded there with
// B(t+2); first use P0 of t+2 = 5-phase lead (~2500 cyc), covering the L2
// scatter latency that killed the single-buffered variant (1-phase lead).
// vmcnt gates (in-order counter): issue order per iter is
//   A(P3)^2, bx^8, A(P4)^2, A(P7)^2, by^8
// vmcnt(10) at P3 leaves {A(P3),bx}; at P7 leaves {A(P7),by} -> forces the
// consumed A-buf and the 5-phase-old B set landed.  Never drains to 0.
// ---------------------------------------------------------------------------
template<typename OUT_T, bool BIAS, bool RELU>
__global__ __launch_bounds__(512, 2)
void gemm_bt2(const f16* __restrict__ A, const f16* __restrict__ Bm,
              OUT_T* __restrict__ C, const float* __restrict__ bias,
              int M, int N, int K, long sA, long sB, long sC)
{
    constexpr int TSZ = 256 * 64;          // f16 elements per A tile buffer
    __shared__ alignas(16) f16 As[2 * TSZ];   // 64 KiB (A only)

    int bx = blockIdx.x, by = blockIdx.y;
    {   // XCD-locality remap (gy % 8 == 0 for all uses)
        const int gx = gridDim.x;
        const int l = by * gx + bx;
        const int W = gx * 8;
        const int ygrp = l / W;
        const int rem = l - ygrp * W;
        bx = rem >> 3;
        by = ygrp * 8 + (rem & 7);
    }
    const int z = blockIdx.z;
    A  += (long)z * sA;
    Bm += (long)z * sB;
    C  += (long)z * sC;

    const int tid  = threadIdx.x;
    const int wid  = tid >> 6;
    const int lane = tid & 63;
    const int lr = lane & 31;
    const int lh = lane >> 5;
    const int m0 = by * 256;
    const int n0 = bx * 256;
    const int wm = (wid >> 2) * 128;       // wave row: 0 or 128
    const int wn = (wid & 3) * 64;         // wave col: 0,64,128,192

    // A staging: one GLDS call covers 64 rows (8 rows/wave, 8 x 16B slots).
    // LDS row r slot s holds source k-segment (s ^ (r&7))  [XOR swizzle]
    const int sr = tid >> 3;
    const int sg = ((tid & 7) ^ (sr & 7)) * 8;
    const f16* agS = A + (long)(m0 + sr) * K + sg;
    f16* aD = As + wid * (8 * 64);                   // wave-uniform LDS base

    // A fragment read: k-segment g = 2*ks + lh at slot g ^ (row&7)
    const int s7  = lr & 7;
    const int xs0 = ((0 + lh) ^ s7) * 8;
    const int xs1 = ((2 + lh) ^ s7) * 8;
    const int xs2 = ((4 + lh) ^ s7) * 8;
    const int xs3 = ((6 + lh) ^ s7) * 8;
    const f16* aR = As + (wm + lr) * 64;

    // B fragment global pointers: frag(grp,ks) = Bm[n0+wn+grp*32+lr][kt+ks*16+lh*8]
    const f16* bgl0 = Bm + (long)(n0 + wn + lr) * K + lh * 8;
    const f16* bgl1 = bgl0 + (long)32 * K;

    f32x16 acc[4][2];
#pragma unroll
    for (int mi = 0; mi < 4; ++mi)
#pragma unroll
        for (int ni = 0; ni < 2; ++ni)
#pragma unroll
            for (int r = 0; r < 16; ++r) acc[mi][ni][r] = 0.f;

    f16x8 bx0, bx1, bx2, bx3, bx4, bx5, bx6, bx7;   // B set: even K-tiles
    f16x8 by0, by1, by2, by3, by4, by5, by6, by7;   // B set: odd K-tiles

    const int NT = K >> 6;

#define GAc(buf, R0, kt) GLDS(agS + (long)(R0) * K + (kt), aD + (buf) * TSZ + (R0) * 64)
// B reload into set S: pinned after the MFMA cluster (sched_barrier) so the
// loads can't hoist above the last use of the previous values.
#define BLDS(S, kt) __builtin_amdgcn_sched_barrier(0); \
    S##0 = *(const f16x8*)(bgl0 + (kt));      S##1 = *(const f16x8*)(bgl0 + (kt) + 16); \
    S##2 = *(const f16x8*)(bgl0 + (kt) + 32); S##3 = *(const f16x8*)(bgl0 + (kt) + 48); \
    S##4 = *(const f16x8*)(bgl1 + (kt));      S##5 = *(const f16x8*)(bgl1 + (kt) + 16); \
    S##6 = *(const f16x8*)(bgl1 + (kt) + 32); S##7 = *(const f16x8*)(bgl1 + (kt) + 48);

    // prologue issue order: bx^8, A0^4, A1head^2, by^8 ; vmcnt(10) forces
    // bx+A0 landed, leaves {A1head, by} in flight.
    BLDS(bx, 0)
    GAc(0,   0, 0);  GAc(0,  64, 0);  GAc(0, 128, 0);  GAc(0, 192, 0);
    GAc(1,   0, 64); GAc(1, 128, 64);
    BLDS(by, 64)
    asm volatile("s_waitcnt vmcnt(10)" ::: "memory");
    __builtin_amdgcn_s_barrier();

#define MFMA8(mi, S) \
    acc[mi][0] = __builtin_amdgcn_mfma_f32_32x32x16_f16(af0, S##0, acc[mi][0], 0, 0, 0); \
    acc[mi][1] = __builtin_amdgcn_mfma_f32_32x32x16_f16(af0, S##4, acc[mi][1], 0, 0, 0); \
    acc[mi][0] = __builtin_amdgcn_mfma_f32_32x32x16_f16(af1, S##1, acc[mi][0], 0, 0, 0); \
    acc[mi][1] = __builtin_amdgcn_mfma_f32_32x32x16_f16(af1, S##5, acc[mi][1], 0, 0, 0); \
    acc[mi][0] = __builtin_amdgcn_mfma_f32_32x32x16_f16(af2, S##2, acc[mi][0], 0, 0, 0); \
    acc[mi][1] = __builtin_amdgcn_mfma_f32_32x32x16_f16(af2, S##6, acc[mi][1], 0, 0, 0); \
    acc[mi][0] = __builtin_amdgcn_mfma_f32_32x32x16_f16(af3, S##3, acc[mi][0], 0, 0, 0); \
    acc[mi][1] = __builtin_amdgcn_mfma_f32_32x32x16_f16(af3, S##7, acc[mi][1], 0, 0, 0);

// Phase: 4 A ds_reads | GLDS issues | barrier | lgkm0 | 8 MFMA | [B reload]
//        | [vmcnt gate] | barrier
#define PH(buf, mi, S, VW, BL, ...) { \
    f16x8 af0 = *(const f16x8*)(aR + (buf) * TSZ + (mi) * 2048 + xs0); \
    f16x8 af1 = *(const f16x8*)(aR + (buf) * TSZ + (mi) * 2048 + xs1); \
    f16x8 af2 = *(const f16x8*)(aR + (buf) * TSZ + (mi) * 2048 + xs2); \
    f16x8 af3 = *(const f16x8*)(aR + (buf) * TSZ + (mi) * 2048 + xs3); \
    __VA_ARGS__ \
    __builtin_amdgcn_s_barrier(); \
    asm volatile("s_waitcnt lgkmcnt(0)" ::: "memory"); \
    __builtin_amdgcn_s_setprio(1); \
    MFMA8(mi, S) \
    __builtin_amdgcn_s_setprio(0); \
    BL \
    if (VW) { asm volatile("s_waitcnt vmcnt(10)" ::: "memory"); } \
    __builtin_amdgcn_s_barrier(); \
}

    for (int i = 0; i < NT / 2; ++i) {
        const long k1 = (long)(2 * i + 1) << 6;                           // tile t+1
        const long kA = (2 * i + 2 < NT) ? ((long)(2 * i + 2) << 6) : 0;  // tile t+2
        const long kB = (2 * i + 3 < NT) ? ((long)(2 * i + 3) << 6) : 0;  // tile t+3
        PH(0, 0, bx, 0, ,             GAc(1,  64, k1); GAc(1, 192, k1);)
        PH(0, 1, bx, 0, ,             )
        PH(0, 2, bx, 0, ,             )
        PH(0, 3, bx, 1, BLDS(bx, kA), GAc(0,   0, kA); GAc(0, 128, kA);)  // bx <- B(t+2)
        PH(1, 0, by, 0, ,             GAc(0,  64, kA); GAc(0, 192, kA);)
        PH(1, 1, by, 0, ,             )
        PH(1, 2, by, 0, ,             )
        PH(1, 3, by, 1, BLDS(by, kB), GAc(1,   0, kB); GAc(1, 128, kB);)  // by <- B(t+3)
    }

    asm volatile("s_waitcnt vmcnt(0)" ::: "memory");    // drain before LDS dealloc

    // C/D layout (32x32): col = lane&31, row = (reg&3) + 8*(reg>>2) + 4*(lane>>5)
#pragma unroll
    for (int ni = 0; ni < 2; ++ni) {
        const int gc = n0 + wn + ni * 32 + lr;
        const float bv = BIAS ? bias[gc] : 0.0f;
#pragma unroll
        for (int mi = 0; mi < 4; ++mi) {
#pragma unroll
            for (int r = 0; r < 16; ++r) {
                const int row = (r & 3) + 8 * (r >> 2) + 4 * lh;
                const int gr = m0 + wm + mi * 32 + row;
                float v = acc[mi][ni][r] + bv;
                if (RELU) v = fmaxf(v, 0.0f);
                C[(long)gr * N + gc] = (OUT_T)v;
            }
        }
    }
#undef PH
#undef MFMA8
#undef BLDS
#undef GAc
}

// ---------------------------------------------------------------------------
// 256x128 tile, BK=64, 512 threads (8 waves 4M x 2N, 64x64 per wave),
// 4-phase K-loop, B through LDS (proven R2 form — B here is L3-resident qBt,
// where a short direct-load lead would stall).  LDS 96 KiB, XOR-swizzled.
//   P0(buf0,mi0): A1-fill x4 (tile 2i+1)
//   P1(buf0,mi1): B0-fill x2 (tile 2i+2) + vmcnt(2) -> buf1 landed
//   P2(buf1,mi0): A0-fill x4 (tile 2i+2)
//   P3(buf1,mi1): B1-fill x2 (tile 2i+3) + vmcnt(2) -> buf0 landed
// ---------------------------------------------------------------------------
template<typename OUT_T, bool BIAS, bool RELU>
__global__ __launch_bounds__(512, 2)
void gemm_bt3(const f16* __restrict__ A, const f16* __restrict__ Bm,
              OUT_T* __restrict__ C, const float* __restrict__ bias,
              int M, int N, int K, long sA, long sB, long sC)
{
    constexpr int TSA = 256 * 64;
    constexpr int TSB = 128 * 64;
    __shared__ alignas(16) f16 As[2 * TSA];
    __shared__ alignas(16) f16 Bs[2 * TSB];

    int bx = blockIdx.x, by = blockIdx.y;
    {   // XCD-locality remap (gy % 8 == 0 for all uses)
        const int gx = gridDim.x;
        const int l = by * gx + bx;
        const int W = gx * 8;
        const int ygrp = l / W;
        const int rem = l - ygrp * W;
        bx = rem >> 3;
        by = ygrp * 8 + (rem & 7);
    }
    const int z = blockIdx.z;
    A  += (long)z * sA;
    Bm += (long)z * sB;
    C  += (long)z * sC;

    const int tid  = threadIdx.x;
    const int wid  = tid >> 6;
    const int lane = tid & 63;
    const int lr = lane & 31;
    const int lh = lane >> 5;
    const int m0 = by * 256;
    const int n0 = bx * 128;
    const int wm = (wid >> 1) * 64;        // 4 M-waves: 0,64,128,192
    const int wn = (wid & 1) * 64;         // 2 N-waves: 0,64

    const int sr = tid >> 3;
    const int sg = ((tid & 7) ^ (sr & 7)) * 8;
    const f16* agS = A  + (long)(m0 + sr) * K + sg;
    const f16* bgS = Bm + (long)(n0 + sr) * K + sg;
    f16* aD = As + wid * (8 * 64);
    f16* bD = Bs + wid * (8 * 64);

    const int s7  = lr & 7;
    const int xs0 = ((0 + lh) ^ s7) * 8;
    const int xs1 = ((2 + lh) ^ s7) * 8;
    const int xs2 = ((4 + lh) ^ s7) * 8;
    const int xs3 = ((6 + lh) ^ s7) * 8;
    const f16* aR = As + (wm + lr) * 64;
    const f16* bR = Bs + (wn + lr) * 64;

    f32x16 acc[2][2];
#pragma unroll
    for (int mi = 0; mi < 2; ++mi)
#pragma unroll
        for (int ni = 0; ni < 2; ++ni)
#pragma unroll
            for (int r = 0; r < 16; ++r) acc[mi][ni][r] = 0.f;

    f16x8 b00, b01, b02, b03, b10, b11, b12, b13;

    const int NT = K >> 6;

#define GA3(buf, R0, kt) GLDS(agS + (long)(R0) * K + (kt), aD + (buf) * TSA + (R0) * 64)
#define GB3(buf, R0, kt) GLDS(bgS + (long)(R0) * K + (kt), bD + (buf) * TSB + (R0) * 64)

    // prologue: buf0 full (6 = oldest), buf1 B (2).  invariant: 2 outstanding.
    GB3(0,   0, 0);  GB3(0,  64, 0);
    GA3(0,   0, 0);  GA3(0,  64, 0);  GA3(0, 128, 0);  GA3(0, 192, 0);
    GB3(1,   0, 64); GB3(1,  64, 64);
    asm volatile("s_waitcnt vmcnt(2)" ::: "memory");   // buf0 fully landed
    __builtin_amdgcn_s_barrier();

#define MFMA8_3(mi) \
    acc[mi][0] = __builtin_amdgcn_mfma_f32_32x32x16_f16(af0, b00, acc[mi][0], 0, 0, 0); \
    acc[mi][1] = __builtin_amdgcn_mfma_f32_32x32x16_f16(af0, b10, acc[mi][1], 0, 0, 0); \
    acc[mi][0] = __builtin_amdgcn_mfma_f32_32x32x16_f16(af1, b01, acc[mi][0], 0, 0, 0); \
    acc[mi][1] = __builtin_amdgcn_mfma_f32_32x32x16_f16(af1, b11, acc[mi][1], 0, 0, 0); \
    acc[mi][0] = __builtin_amdgcn_mfma_f32_32x32x16_f16(af2, b02, acc[mi][0], 0, 0, 0); \
    acc[mi][1] = __builtin_amdgcn_mfma_f32_32x32x16_f16(af2, b12, acc[mi][1], 0, 0, 0); \
    acc[mi][0] = __builtin_amdgcn_mfma_f32_32x32x16_f16(af3, b03, acc[mi][0], 0, 0, 0); \
    acc[mi][1] = __builtin_amdgcn_mfma_f32_32x32x16_f16(af3, b13, acc[mi][1], 0, 0, 0);

#define PH3(buf, mi, VW, ...) { \
    if ((mi) == 0) { \
        b00 = *(const f16x8*)(bR + (buf) * TSB + xs0); \
        b01 = *(const f16x8*)(bR + (buf) * TSB + xs1); \
        b02 = *(const f16x8*)(bR + (buf) * TSB + xs2); \
        b03 = *(const f16x8*)(bR + (buf) * TSB + xs3); \
        b10 = *(const f16x8*)(bR + (buf) * TSB + 2048 + xs0); \
        b11 = *(const f16x8*)(bR + (buf) * TSB + 2048 + xs1); \
        b12 = *(const f16x8*)(bR + (buf) * TSB + 2048 + xs2); \
        b13 = *(const f16x8*)(bR + (buf) * TSB + 2048 + xs3); \
    } \
    f16x8 af0 = *(const f16x8*)(aR + (buf) * TSA + (mi) * 2048 + xs0); \
    f16x8 af1 = *(const f16x8*)(aR + (buf) * TSA + (mi) * 2048 + xs1); \
    f16x8 af2 = *(const f16x8*)(aR + (buf) * TSA + (mi) * 2048 + xs2); \
    f16x8 af3 = *(const f16x8*)(aR + (buf) * TSA + (mi) * 2048 + xs3); \
    __VA_ARGS__ \
    __builtin_amdgcn_s_barrier(); \
    asm volatile("s_waitcnt lgkmcnt(0)" ::: "memory"); \
    __builtin_amdgcn_s_setprio(1); \
    MFMA8_3(mi) \
    __builtin_amdgcn_s_setprio(0); \
    if (VW) { asm volatile("s_waitcnt vmcnt(2)" ::: "memory"); } \
    __builtin_amdgcn_s_barrier(); \
}

    for (int i = 0; i < NT / 2; ++i) {
        const long k1 = (long)(2 * i + 1) << 6;                           // tile t+1
        const long kA = (2 * i + 2 < NT) ? ((long)(2 * i + 2) << 6) : 0;  // tile t+2
        const long kB = (2 * i + 3 < NT) ? ((long)(2 * i + 3) << 6) : 0;  // tile t+3
        PH3(0, 0, 0, GA3(1,   0, k1); GA3(1,  64, k1); GA3(1, 128, k1); GA3(1, 192, k1);)
        PH3(0, 1, 1, GB3(0,   0, kA); GB3(0,  64, kA);)
        PH3(1, 0, 0, GA3(0,   0, kA); GA3(0,  64, kA); GA3(0, 128, kA); GA3(0, 192, kA);)
        PH3(1, 1, 1, GB3(1,   0, kB); GB3(1,  64, kB);)
    }

    asm volatile("s_waitcnt vmcnt(0)" ::: "memory");

    // C/D layout (32x32): col = lane&31, row = (reg&3) + 8*(reg>>2) + 4*(lane>>5)
#pragma unroll
    for (int ni = 0; ni < 2; ++ni) {
        const int gc = n0 + wn + ni * 32 + lr;
        const float bv = BIAS ? bias[gc] : 0.0f;
#pragma unroll
        for (int mi = 0; mi < 2; ++mi) {
#pragma unroll
            for (int r = 0; r < 16; ++r) {
                const int row = (r & 3) + 8 * (r >> 2) + 4 * lh;
                const int gr = m0 + wm + mi * 32 + row;
                float v = acc[mi][ni][r] + bv;
                if (RELU) v = fmaxf(v, 0.0f);
                C[(long)gr * N + gc] = (OUT_T)v;
            }
        }
    }
#undef PH3
#undef MFMA8_3
#undef GA3
#undef GB3
}

// ---------------------------------------------------------------------------
__global__ __launch_bounds__(256)
void cast_f32_f16(const float* __restrict__ X, f16* __restrict__ Y)
{
    const long i = ((long)blockIdx.x * 256 + threadIdx.x) * 8;
    float4 a = *(const float4*)(X + i);
    float4 b = *(const float4*)(X + i + 4);
    f16x8 h = {(f16)a.x, (f16)a.y, (f16)a.z, (f16)a.w,
               (f16)b.x, (f16)b.y, (f16)b.z, (f16)b.w};
    *(f16x8*)(Y + i) = h;
}

// proj_q fp32 [2048 x 1024] per batch -> qB fp16 (row-major) AND qBt fp16 [1024 x 2048]
__global__ __launch_bounds__(256)
void cast_q_dual(const float* __restrict__ X, f16* __restrict__ Yrow,
                 f16* __restrict__ Ytr)
{
    __shared__ f16 t[64][72];
    const float* Xb = X + (long)blockIdx.z * (2048L * 1024);
    f16* Yrb = Yrow + (long)blockIdx.z * (2048L * 1024);
    f16* Ytb = Ytr  + (long)blockIdx.z * (1024L * 2048);
    const int r0 = blockIdx.y * 64;
    const int c0 = blockIdx.x * 64;
    const int tid = threadIdx.x;
    const int tr = tid >> 4;
    const int tc = (tid & 15) * 4;
#pragma unroll
    for (int rr = 0; rr < 64; rr += 16) {
        float4 v = *(const float4*)(Xb + (long)(r0 + tr + rr) * 1024 + c0 + tc);
        f16x4 h = {(f16)v.x, (f16)v.y, (f16)v.z, (f16)v.w};
        *(f16x4*)&t[tr + rr][tc] = h;
        *(f16x4*)(Yrb + (long)(r0 + tr + rr) * 1024 + c0 + tc) = h;
    }
    __syncthreads();
#pragma unroll
    for (int rr = 0; rr < 64; rr += 16) {
        const int orow = tr + rr;
        f16x4 o = {t[tc + 0][orow], t[tc + 1][orow], t[tc + 2][orow], t[tc + 3][orow]};
        *(f16x4*)(Ytb + (long)(c0 + orow) * 2048 + r0 + tc) = o;
    }
}

// rowwise softmax over 2048 fp32 -> fp16
__global__ __launch_bounds__(256)
void softmax_p(const float* __restrict__ S, f16* __restrict__ P)
{
    const long row = blockIdx.x;
    const float* s = S + row * 2048;
    f16* p = P + row * 2048;
    const int tid = threadIdx.x;
    const int wid = tid >> 6, lane = tid & 63;

    float4 a = *(const float4*)(s + tid * 8);
    float4 b = *(const float4*)(s + tid * 8 + 4);
    float v[8] = {a.x, a.y, a.z, a.w, b.x, b.y, b.z, b.w};

    float m = v[0];
#pragma unroll
    for (int j = 1; j < 8; ++j) m = fmaxf(m, v[j]);
#pragma unroll
    for (int off = 32; off > 0; off >>= 1) m = fmaxf(m, __shfl_xor(m, off, 64));

    __shared__ float red[8];
    if (lane == 0) red[wid] = m;
    __syncthreads();
    m = fmaxf(fmaxf(red[0], red[1]), fmaxf(red[2], red[3]));

    float sum = 0.f;
#pragma unroll
    for (int j = 0; j < 8; ++j) { v[j] = __expf(v[j] - m); sum += v[j]; }
#pragma unroll
    for (int off = 32; off > 0; off >>= 1) sum += __shfl_xor(sum, off, 64);
    if (lane == 0) red[4 + wid] = sum;
    __syncthreads();
    sum = red[4] + red[5] + red[6] + red[7];

    const float inv = 1.0f / sum;
    f16x8 h = {(f16)(v[0] * inv), (f16)(v[1] * inv), (f16)(v[2] * inv), (f16)(v[3] * inv),
               (f16)(v[4] * inv), (f16)(v[5] * inv), (f16)(v[6] * inv), (f16)(v[7] * inv)};
    *(f16x8*)(p + tid * 8) = h;
}

// ---------------------------------------------------------------------------
extern "C" void kernel_launch(void* const* d_in, const int* in_sizes, int n_in,
                              void* d_out, int out_size, void* d_ws, size_t ws_size,
                              hipStream_t stream)
{
    const float* proj_p = (const float*)d_in[0];  // [16,2048,1024]
    const float* proj_q = (const float*)d_in[1];  // [16,2048,1024]
    const float* W      = (const float*)d_in[2];  // [1024,1024]
    const float* bias   = (const float*)d_in[3];  // [1024]
    float* out = (float*)d_out;

    constexpr long Bc = 16, L = 2048, H = 1024, NB = 4;
    constexpr long nPQ = Bc * L * H;              // 33,554,432 elements

    char* ws = (char*)d_ws;
    f16*   pB  = (f16*)(ws + 0L);                 // 67,108,864 B
    f16*   qB  = (f16*)(ws + 67108864L);          // 67,108,864 B
    f16*   qBt = (f16*)(ws + 134217728L);         // 67,108,864 B  [B][H][L]
    f16*   tQ  = (f16*)(ws + 201326592L);         // 67,108,864 B
    f16*   aV  = (f16*)(ws + 268435456L);         // 67,108,864 B
    f16*   Wb  = (f16*)(ws + 335544320L);         //  2,097,152 B
    float* S   = (float*)(ws + 337641472L);       // 67,108,864 B (4 batches fp32)
    f16*   P   = (f16*)(ws + 404750336L);         // 33,554,432 B (4 batches fp16)

    cast_f32_f16<<<nPQ / (256 * 8), 256, 0, stream>>>(proj_p, pB);
    cast_f32_f16<<<(H * H) / (256 * 8), 256, 0, stream>>>(W, Wb);
    cast_q_dual<<<dim3(16, 32, 16), 256, 0, stream>>>(proj_q, qB, qBt);

    // G1: tQ[b,q,o] = qB[b,q,:] . Wb[o,:] + bias[o]   (256-tile 8-phase)
    gemm_bt2<f16, true, false><<<dim3(H / 256, (Bc * L) / 256, 1), 512, 0, stream>>>(
        qB, Wb, tQ, bias, (int)(Bc * L), (int)H, (int)H, 0, 0, 0);

    for (int c = 0; c < 4; ++c) {
        const long boff = (long)c * NB * L * H;
        // G2: S[p,q] = pB[p,:] . tQ[q,:]   (fp32 out, 256-tile 8-phase)
        gemm_bt2<float, false, false><<<dim3(L / 256, L / 256, NB), 512, 0, stream>>>(
            pB + boff, tQ + boff, S, nullptr, (int)L, (int)L, (int)H,
            L * H, L * H, L * L);
        // softmax rows -> P fp16
        softmax_p<<<NB * L, 256, 0, stream>>>(S, P);
        // G3: aV[p,h] = P[p,:] . qBt[h,:]   (256x128-tile 4-phase, K=2048)
        gemm_bt3<f16, false, false><<<dim3(H / 128, L / 256, NB), 512, 0, stream>>>(
            P, qBt + (long)c * NB * H * L, aV + boff, nullptr, (int)L, (int)H, (int)L,
            L * L, H * L, L * H);
    }

    // G4: out = relu(aV . Wb^T + bias)  (fp32 out, 256-tile 8-phase)
    gemm_bt2<float, false, true><<<dim3(H / 256, (Bc * L) / 256, 1), 512, 0, stream>>>(
        aV, Wb, out, bias, (int)(Bc * L), (int)H, (int)H, 0, 0, 0);
}

// Round 5
// 941.031 us; speedup vs baseline: 1.4076x; 1.1694x over previous
//
#include <hip/hip_runtime.h>

typedef _Float16 f16;
typedef _Float16 f16x8 __attribute__((ext_vector_type(8)));
typedef _Float16 f16x4 __attribute__((ext_vector_type(4)));
typedef float    f32x16 __attribute__((ext_vector_type(16)));

#define GLDS(gp, lp) __builtin_amdgcn_global_load_lds( \
    (const __attribute__((address_space(1))) void*)(gp), \
    (__attribute__((address_space(3))) void*)(lp), 16, 0, 0)

// ---------------------------------------------------------------------------
// 256x256 tile, BK=64, 512 threads (8 waves 2x4, 128x64 per wave), 8-phase
// K-loop with counted vmcnt(6) prefetch, LDS XOR-swizzle, s_setprio around
// MFMA clusters.  Double-buffered 128 KiB LDS (A and B both staged via
// global_load_lds — B-direct-from-global was tried and regressed 1.5x:
// per-lane row-scatter B loads thrash L2).
// NOTE: no explicit lgkmcnt(0) before the MFMA cluster — the ds_reads are
// plain loads, so the compiler emits progressive lgkmcnt(N) per dependent
// MFMA, letting the LDS unit serve later frags while early MFMAs run.
// ---------------------------------------------------------------------------
template<typename OUT_T, bool BIAS, bool RELU>
__global__ __launch_bounds__(512, 2)
void gemm_bt2(const f16* __restrict__ A, const f16* __restrict__ Bm,
              OUT_T* __restrict__ C, const float* __restrict__ bias,
              int M, int N, int K, long sA, long sB, long sC)
{
    constexpr int TSZ = 256 * 64;          // f16 elements per tile buffer
    __shared__ alignas(16) f16 As[2 * TSZ];
    __shared__ alignas(16) f16 Bs[2 * TSZ];

    int bx = blockIdx.x, by = blockIdx.y;
    {   // XCD-locality remap (gy % 8 == 0 for all uses)
        const int gx = gridDim.x;
        const int l = by * gx + bx;
        const int W = gx * 8;
        const int ygrp = l / W;
        const int rem = l - ygrp * W;
        bx = rem >> 3;
        by = ygrp * 8 + (rem & 7);
    }
    const int z = blockIdx.z;
    A  += (long)z * sA;
    Bm += (long)z * sB;
    C  += (long)z * sC;

    const int tid  = threadIdx.x;
    const int wid  = tid >> 6;
    const int lane = tid & 63;
    const int lr = lane & 31;
    const int lh = lane >> 5;
    const int m0 = by * 256;
    const int n0 = bx * 256;
    const int wm = (wid >> 2) * 128;       // wave row: 0 or 128
    const int wn = (wid & 3) * 64;         // wave col: 0,64,128,192

    // staging: one GLDS call covers 64 rows (8 rows/wave, 8 x 16B slots/row).
    // LDS row r slot s holds source k-segment (s ^ (r&7))  [XOR swizzle]
    const int sr = tid >> 3;                         // row within 64-row call
    const int sg = ((tid & 7) ^ (sr & 7)) * 8;       // pre-swizzled source col
    const f16* agS = A  + (long)(m0 + sr) * K + sg;
    const f16* bgS = Bm + (long)(n0 + sr) * K + sg;
    f16* aD = As + wid * (8 * 64);                   // wave-uniform LDS base
    f16* bD = Bs + wid * (8 * 64);

    // fragment read: k-segment g = 2*ks + lh at slot g ^ (row&7)
    const int s7  = lr & 7;
    const int xs0 = ((0 + lh) ^ s7) * 8;
    const int xs1 = ((2 + lh) ^ s7) * 8;
    const int xs2 = ((4 + lh) ^ s7) * 8;
    const int xs3 = ((6 + lh) ^ s7) * 8;
    const f16* aR = As + (wm + lr) * 64;
    const f16* bR = Bs + (wn + lr) * 64;

    f32x16 acc[4][2];
#pragma unroll
    for (int mi = 0; mi < 4; ++mi)
#pragma unroll
        for (int ni = 0; ni < 2; ++ni)
#pragma unroll
            for (int r = 0; r < 16; ++r) acc[mi][ni][r] = 0.f;

    f16x8 b00, b01, b02, b03, b10, b11, b12, b13;

    const int NT = K >> 6;

#define GAc(buf, R0, kt) GLDS(agS + (long)(R0) * K + (kt), aD + (buf) * TSZ + (R0) * 64)
#define GBc(buf, R0, kt) GLDS(bgS + (long)(R0) * K + (kt), bD + (buf) * TSZ + (R0) * 64)

    // prologue: tile0 -> buf0 (B then A = oldest 8), tile1 -> buf1 (B all, A head)
    GBc(0,   0, 0);  GBc(0,  64, 0);  GBc(0, 128, 0);  GBc(0, 192, 0);
    GAc(0,   0, 0);  GAc(0,  64, 0);  GAc(0, 128, 0);  GAc(0, 192, 0);
    GBc(1,   0, 64); GBc(1,  64, 64); GBc(1, 128, 64); GBc(1, 192, 64);
    GAc(1,   0, 64); GAc(1, 128, 64);
    asm volatile("s_waitcnt vmcnt(6)" ::: "memory");   // buf0 fully landed
    __builtin_amdgcn_s_barrier();

#define MFMA8(mi) \
    acc[mi][0] = __builtin_amdgcn_mfma_f32_32x32x16_f16(af0, b00, acc[mi][0], 0, 0, 0); \
    acc[mi][1] = __builtin_amdgcn_mfma_f32_32x32x16_f16(af0, b10, acc[mi][1], 0, 0, 0); \
    acc[mi][0] = __builtin_amdgcn_mfma_f32_32x32x16_f16(af1, b01, acc[mi][0], 0, 0, 0); \
    acc[mi][1] = __builtin_amdgcn_mfma_f32_32x32x16_f16(af1, b11, acc[mi][1], 0, 0, 0); \
    acc[mi][0] = __builtin_amdgcn_mfma_f32_32x32x16_f16(af2, b02, acc[mi][0], 0, 0, 0); \
    acc[mi][1] = __builtin_amdgcn_mfma_f32_32x32x16_f16(af2, b12, acc[mi][1], 0, 0, 0); \
    acc[mi][0] = __builtin_amdgcn_mfma_f32_32x32x16_f16(af3, b03, acc[mi][0], 0, 0, 0); \
    acc[mi][1] = __builtin_amdgcn_mfma_f32_32x32x16_f16(af3, b13, acc[mi][1], 0, 0, 0);

// Phase: frag ds_reads | GLDS issues | barrier | 8 MFMA (compiler inserts
// progressive lgkmcnt per frag dependency) | [vmcnt gate] | barrier
#define PH(buf, mi, VW, ...) { \
    f16x8 af0 = *(const f16x8*)(aR + (buf) * TSZ + (mi) * 2048 + xs0); \
    f16x8 af1 = *(const f16x8*)(aR + (buf) * TSZ + (mi) * 2048 + xs1); \
    f16x8 af2 = *(const f16x8*)(aR + (buf) * TSZ + (mi) * 2048 + xs2); \
    f16x8 af3 = *(const f16x8*)(aR + (buf) * TSZ + (mi) * 2048 + xs3); \
    if ((mi) == 0) { \
        b00 = *(const f16x8*)(bR + (buf) * TSZ + xs0); \
        b01 = *(const f16x8*)(bR + (buf) * TSZ + xs1); \
        b02 = *(const f16x8*)(bR + (buf) * TSZ + xs2); \
        b03 = *(const f16x8*)(bR + (buf) * TSZ + xs3); \
        b10 = *(const f16x8*)(bR + (buf) * TSZ + 2048 + xs0); \
        b11 = *(const f16x8*)(bR + (buf) * TSZ + 2048 + xs1); \
        b12 = *(const f16x8*)(bR + (buf) * TSZ + 2048 + xs2); \
        b13 = *(const f16x8*)(bR + (buf) * TSZ + 2048 + xs3); \
    } \
    __VA_ARGS__ \
    __builtin_amdgcn_s_barrier(); \
    __builtin_amdgcn_s_setprio(1); \
    MFMA8(mi) \
    __builtin_amdgcn_s_setprio(0); \
    if (VW) { asm volatile("s_waitcnt vmcnt(6)" ::: "memory"); } \
    __builtin_amdgcn_s_barrier(); \
}

    for (int i = 0; i < NT / 2; ++i) {
        const long k1 = (long)(2 * i + 1) << 6;                           // tile t+1 (tail)
        const long kA = (2 * i + 2 < NT) ? ((long)(2 * i + 2) << 6) : 0;  // tile t+2
        const long kB = (2 * i + 3 < NT) ? ((long)(2 * i + 3) << 6) : 0;  // tile t+3
        PH(0, 0, 0, GAc(1,  64, k1); GAc(1, 192, k1);)
        PH(0, 1, 0, GBc(0,   0, kA); GBc(0,  64, kA);)
        PH(0, 2, 0, GBc(0, 128, kA); GBc(0, 192, kA);)
        PH(0, 3, 1, GAc(0,   0, kA); GAc(0, 128, kA);)
        PH(1, 0, 0, GAc(0,  64, kA); GAc(0, 192, kA);)
        PH(1, 1, 0, GBc(1,   0, kB); GBc(1,  64, kB);)
        PH(1, 2, 0, GBc(1, 128, kB); GBc(1, 192, kB);)
        PH(1, 3, 1, GAc(1,   0, kB); GAc(1, 128, kB);)
    }

    asm volatile("s_waitcnt vmcnt(0)" ::: "memory");    // drain before LDS dealloc

    // C/D layout (32x32): col = lane&31, row = (reg&3) + 8*(reg>>2) + 4*(lane>>5)
#pragma unroll
    for (int ni = 0; ni < 2; ++ni) {
        const int gc = n0 + wn + ni * 32 + lr;
        const float bv = BIAS ? bias[gc] : 0.0f;
#pragma unroll
        for (int mi = 0; mi < 4; ++mi) {
#pragma unroll
            for (int r = 0; r < 16; ++r) {
                const int row = (r & 3) + 8 * (r >> 2) + 4 * lh;
                const int gr = m0 + wm + mi * 32 + row;
                float v = acc[mi][ni][r] + bv;
                if (RELU) v = fmaxf(v, 0.0f);
                C[(long)gr * N + gc] = (OUT_T)v;
            }
        }
    }
#undef PH
#undef MFMA8
#undef GAc
#undef GBc
}

// ---------------------------------------------------------------------------
// 256x128 tile, BK=64, 512 threads (8 waves 4M x 2N, 64x64 per wave),
// 4-phase K-loop, B through LDS.  LDS 96 KiB, XOR-swizzled.  Grid fills 256
// CUs for M=2048,N=1024 shapes.  Same no-lgkmcnt(0) policy as gemm_bt2.
//   P0(buf0,mi0): A1-fill x4 (tile 2i+1)
//   P1(buf0,mi1): B0-fill x2 (tile 2i+2) + vmcnt(2) -> buf1 landed
//   P2(buf1,mi0): A0-fill x4 (tile 2i+2)
//   P3(buf1,mi1): B1-fill x2 (tile 2i+3) + vmcnt(2) -> buf0 landed
// ---------------------------------------------------------------------------
template<typename OUT_T, bool BIAS, bool RELU>
__global__ __launch_bounds__(512, 2)
void gemm_bt3(const f16* __restrict__ A, const f16* __restrict__ Bm,
              OUT_T* __restrict__ C, const float* __restrict__ bias,
              int M, int N, int K, long sA, long sB, long sC)
{
    constexpr int TSA = 256 * 64;
    constexpr int TSB = 128 * 64;
    __shared__ alignas(16) f16 As[2 * TSA];
    __shared__ alignas(16) f16 Bs[2 * TSB];

    int bx = blockIdx.x, by = blockIdx.y;
    {   // XCD-locality remap (gy % 8 == 0 for all uses)
        const int gx = gridDim.x;
        const int l = by * gx + bx;
        const int W = gx * 8;
        const int ygrp = l / W;
        const int rem = l - ygrp * W;
        bx = rem >> 3;
        by = ygrp * 8 + (rem & 7);
    }
    const int z = blockIdx.z;
    A  += (long)z * sA;
    Bm += (long)z * sB;
    C  += (long)z * sC;

    const int tid  = threadIdx.x;
    const int wid  = tid >> 6;
    const int lane = tid & 63;
    const int lr = lane & 31;
    const int lh = lane >> 5;
    const int m0 = by * 256;
    const int n0 = bx * 128;
    const int wm = (wid >> 1) * 64;        // 4 M-waves: 0,64,128,192
    const int wn = (wid & 1) * 64;         // 2 N-waves: 0,64

    const int sr = tid >> 3;
    const int sg = ((tid & 7) ^ (sr & 7)) * 8;
    const f16* agS = A  + (long)(m0 + sr) * K + sg;
    const f16* bgS = Bm + (long)(n0 + sr) * K + sg;
    f16* aD = As + wid * (8 * 64);
    f16* bD = Bs + wid * (8 * 64);

    const int s7  = lr & 7;
    const int xs0 = ((0 + lh) ^ s7) * 8;
    const int xs1 = ((2 + lh) ^ s7) * 8;
    const int xs2 = ((4 + lh) ^ s7) * 8;
    const int xs3 = ((6 + lh) ^ s7) * 8;
    const f16* aR = As + (wm + lr) * 64;
    const f16* bR = Bs + (wn + lr) * 64;

    f32x16 acc[2][2];
#pragma unroll
    for (int mi = 0; mi < 2; ++mi)
#pragma unroll
        for (int ni = 0; ni < 2; ++ni)
#pragma unroll
            for (int r = 0; r < 16; ++r) acc[mi][ni][r] = 0.f;

    f16x8 b00, b01, b02, b03, b10, b11, b12, b13;

    const int NT = K >> 6;

#define GA3(buf, R0, kt) GLDS(agS + (long)(R0) * K + (kt), aD + (buf) * TSA + (R0) * 64)
#define GB3(buf, R0, kt) GLDS(bgS + (long)(R0) * K + (kt), bD + (buf) * TSB + (R0) * 64)

    // prologue: buf0 full (6 = oldest), buf1 B (2).  invariant: 2 outstanding.
    GB3(0,   0, 0);  GB3(0,  64, 0);
    GA3(0,   0, 0);  GA3(0,  64, 0);  GA3(0, 128, 0);  GA3(0, 192, 0);
    GB3(1,   0, 64); GB3(1,  64, 64);
    asm volatile("s_waitcnt vmcnt(2)" ::: "memory");   // buf0 fully landed
    __builtin_amdgcn_s_barrier();

#define MFMA8_3(mi) \
    acc[mi][0] = __builtin_amdgcn_mfma_f32_32x32x16_f16(af0, b00, acc[mi][0], 0, 0, 0); \
    acc[mi][1] = __builtin_amdgcn_mfma_f32_32x32x16_f16(af0, b10, acc[mi][1], 0, 0, 0); \
    acc[mi][0] = __builtin_amdgcn_mfma_f32_32x32x16_f16(af1, b01, acc[mi][0], 0, 0, 0); \
    acc[mi][1] = __builtin_amdgcn_mfma_f32_32x32x16_f16(af1, b11, acc[mi][1], 0, 0, 0); \
    acc[mi][0] = __builtin_amdgcn_mfma_f32_32x32x16_f16(af2, b02, acc[mi][0], 0, 0, 0); \
    acc[mi][1] = __builtin_amdgcn_mfma_f32_32x32x16_f16(af2, b12, acc[mi][1], 0, 0, 0); \
    acc[mi][0] = __builtin_amdgcn_mfma_f32_32x32x16_f16(af3, b03, acc[mi][0], 0, 0, 0); \
    acc[mi][1] = __builtin_amdgcn_mfma_f32_32x32x16_f16(af3, b13, acc[mi][1], 0, 0, 0);

#define PH3(buf, mi, VW, ...) { \
    f16x8 af0 = *(const f16x8*)(aR + (buf) * TSA + (mi) * 2048 + xs0); \
    f16x8 af1 = *(const f16x8*)(aR + (buf) * TSA + (mi) * 2048 + xs1); \
    f16x8 af2 = *(const f16x8*)(aR + (buf) * TSA + (mi) * 2048 + xs2); \
    f16x8 af3 = *(const f16x8*)(aR + (buf) * TSA + (mi) * 2048 + xs3); \
    if ((mi) == 0) { \
        b00 = *(const f16x8*)(bR + (buf) * TSB + xs0); \
        b01 = *(const f16x8*)(bR + (buf) * TSB + xs1); \
        b02 = *(const f16x8*)(bR + (buf) * TSB + xs2); \
        b03 = *(const f16x8*)(bR + (buf) * TSB + xs3); \
        b10 = *(const f16x8*)(bR + (buf) * TSB + 2048 + xs0); \
        b11 = *(const f16x8*)(bR + (buf) * TSB + 2048 + xs1); \
        b12 = *(const f16x8*)(bR + (buf) * TSB + 2048 + xs2); \
        b13 = *(const f16x8*)(bR + (buf) * TSB + 2048 + xs3); \
    } \
    __VA_ARGS__ \
    __builtin_amdgcn_s_barrier(); \
    __builtin_amdgcn_s_setprio(1); \
    MFMA8_3(mi) \
    __builtin_amdgcn_s_setprio(0); \
    if (VW) { asm volatile("s_waitcnt vmcnt(2)" ::: "memory"); } \
    __builtin_amdgcn_s_barrier(); \
}

    for (int i = 0; i < NT / 2; ++i) {
        const long k1 = (long)(2 * i + 1) << 6;                           // tile t+1
        const long kA = (2 * i + 2 < NT) ? ((long)(2 * i + 2) << 6) : 0;  // tile t+2
        const long kB = (2 * i + 3 < NT) ? ((long)(2 * i + 3) << 6) : 0;  // tile t+3
        PH3(0, 0, 0, GA3(1,   0, k1); GA3(1,  64, k1); GA3(1, 128, k1); GA3(1, 192, k1);)
        PH3(0, 1, 1, GB3(0,   0, kA); GB3(0,  64, kA);)
        PH3(1, 0, 0, GA3(0,   0, kA); GA3(0,  64, kA); GA3(0, 128, kA); GA3(0, 192, kA);)
        PH3(1, 1, 1, GB3(1,   0, kB); GB3(1,  64, kB);)
    }

    asm volatile("s_waitcnt vmcnt(0)" ::: "memory");

    // C/D layout (32x32): col = lane&31, row = (reg&3) + 8*(reg>>2) + 4*(lane>>5)
#pragma unroll
    for (int ni = 0; ni < 2; ++ni) {
        const int gc = n0 + wn + ni * 32 + lr;
        const float bv = BIAS ? bias[gc] : 0.0f;
#pragma unroll
        for (int mi = 0; mi < 2; ++mi) {
#pragma unroll
            for (int r = 0; r < 16; ++r) {
                const int row = (r & 3) + 8 * (r >> 2) + 4 * lh;
                const int gr = m0 + wm + mi * 32 + row;
                float v = acc[mi][ni][r] + bv;
                if (RELU) v = fmaxf(v, 0.0f);
                C[(long)gr * N + gc] = (OUT_T)v;
            }
        }
    }
#undef PH3
#undef MFMA8_3
#undef GA3
#undef GB3
}

// ---------------------------------------------------------------------------
__global__ __launch_bounds__(256)
void cast_f32_f16(const float* __restrict__ X, f16* __restrict__ Y)
{
    const long i = ((long)blockIdx.x * 256 + threadIdx.x) * 8;
    float4 a = *(const float4*)(X + i);
    float4 b = *(const float4*)(X + i + 4);
    f16x8 h = {(f16)a.x, (f16)a.y, (f16)a.z, (f16)a.w,
               (f16)b.x, (f16)b.y, (f16)b.z, (f16)b.w};
    *(f16x8*)(Y + i) = h;
}

// proj_q fp32 [2048 x 1024] per batch -> qB fp16 (row-major) AND qBt fp16 [1024 x 2048]
__global__ __launch_bounds__(256)
void cast_q_dual(const float* __restrict__ X, f16* __restrict__ Yrow,
                 f16* __restrict__ Ytr)
{
    __shared__ f16 t[64][72];
    const float* Xb = X + (long)blockIdx.z * (2048L * 1024);
    f16* Yrb = Yrow + (long)blockIdx.z * (2048L * 1024);
    f16* Ytb = Ytr  + (long)blockIdx.z * (1024L * 2048);
    const int r0 = blockIdx.y * 64;
    const int c0 = blockIdx.x * 64;
    const int tid = threadIdx.x;
    const int tr = tid >> 4;
    const int tc = (tid & 15) * 4;
#pragma unroll
    for (int rr = 0; rr < 64; rr += 16) {
        float4 v = *(const float4*)(Xb + (long)(r0 + tr + rr) * 1024 + c0 + tc);
        f16x4 h = {(f16)v.x, (f16)v.y, (f16)v.z, (f16)v.w};
        *(f16x4*)&t[tr + rr][tc] = h;
        *(f16x4*)(Yrb + (long)(r0 + tr + rr) * 1024 + c0 + tc) = h;
    }
    __syncthreads();
#pragma unroll
    for (int rr = 0; rr < 64; rr += 16) {
        const int orow = tr + rr;
        f16x4 o = {t[tc + 0][orow], t[tc + 1][orow], t[tc + 2][orow], t[tc + 3][orow]};
        *(f16x4*)(Ytb + (long)(c0 + orow) * 2048 + r0 + tc) = o;
    }
}

// rowwise softmax over 2048 fp32 -> fp16
__global__ __launch_bounds__(256)
void softmax_p(const float* __restrict__ S, f16* __restrict__ P)
{
    const long row = blockIdx.x;
    const float* s = S + row * 2048;
    f16* p = P + row * 2048;
    const int tid = threadIdx.x;
    const int wid = tid >> 6, lane = tid & 63;

    float4 a = *(const float4*)(s + tid * 8);
    float4 b = *(const float4*)(s + tid * 8 + 4);
    float v[8] = {a.x, a.y, a.z, a.w, b.x, b.y, b.z, b.w};

    float m = v[0];
#pragma unroll
    for (int j = 1; j < 8; ++j) m = fmaxf(m, v[j]);
#pragma unroll
    for (int off = 32; off > 0; off >>= 1) m = fmaxf(m, __shfl_xor(m, off, 64));

    __shared__ float red[8];
    if (lane == 0) red[wid] = m;
    __syncthreads();
    m = fmaxf(fmaxf(red[0], red[1]), fmaxf(red[2], red[3]));

    float sum = 0.f;
#pragma unroll
    for (int j = 0; j < 8; ++j) { v[j] = __expf(v[j] - m); sum += v[j]; }
#pragma unroll
    for (int off = 32; off > 0; off >>= 1) sum += __shfl_xor(sum, off, 64);
    if (lane == 0) red[4 + wid] = sum;
    __syncthreads();
    sum = red[4] + red[5] + red[6] + red[7];

    const float inv = 1.0f / sum;
    f16x8 h = {(f16)(v[0] * inv), (f16)(v[1] * inv), (f16)(v[2] * inv), (f16)(v[3] * inv),
               (f16)(v[4] * inv), (f16)(v[5] * inv), (f16)(v[6] * inv), (f16)(v[7] * inv)};
    *(f16x8*)(p + tid * 8) = h;
}

// ---------------------------------------------------------------------------
extern "C" void kernel_launch(void* const* d_in, const int* in_sizes, int n_in,
                              void* d_out, int out_size, void* d_ws, size_t ws_size,
                              hipStream_t stream)
{
    const float* proj_p = (const float*)d_in[0];  // [16,2048,1024]
    const float* proj_q = (const float*)d_in[1];  // [16,2048,1024]
    const float* W      = (const float*)d_in[2];  // [1024,1024]
    const float* bias   = (const float*)d_in[3];  // [1024]
    float* out = (float*)d_out;

    constexpr long Bc = 16, L = 2048, H = 1024, NB = 4;
    constexpr long nPQ = Bc * L * H;              // 33,554,432 elements

    char* ws = (char*)d_ws;
    f16*   pB  = (f16*)(ws + 0L);                 // 67,108,864 B
    f16*   qB  = (f16*)(ws + 67108864L);          // 67,108,864 B
    f16*   qBt = (f16*)(ws + 134217728L);         // 67,108,864 B  [B][H][L]
    f16*   tQ  = (f16*)(ws + 201326592L);         // 67,108,864 B
    f16*   aV  = (f16*)(ws + 268435456L);         // 67,108,864 B
    f16*   Wb  = (f16*)(ws + 335544320L);         //  2,097,152 B
    float* S   = (float*)(ws + 337641472L);       // 67,108,864 B (4 batches fp32)
    f16*   P   = (f16*)(ws + 404750336L);         // 33,554,432 B (4 batches fp16)

    cast_f32_f16<<<nPQ / (256 * 8), 256, 0, stream>>>(proj_p, pB);
    cast_f32_f16<<<(H * H) / (256 * 8), 256, 0, stream>>>(W, Wb);
    cast_q_dual<<<dim3(16, 32, 16), 256, 0, stream>>>(proj_q, qB, qBt);

    // G1: tQ[b,q,o] = qB[b,q,:] . Wb[o,:] + bias[o]   (256-tile 8-phase)
    gemm_bt2<f16, true, false><<<dim3(H / 256, (Bc * L) / 256, 1), 512, 0, stream>>>(
        qB, Wb, tQ, bias, (int)(Bc * L), (int)H, (int)H, 0, 0, 0);

    for (int c = 0; c < 4; ++c) {
        const long boff = (long)c * NB * L * H;
        // G2: S[p,q] = pB[p,:] . tQ[q,:]   (fp32 out, 256-tile 8-phase)
        gemm_bt2<float, false, false><<<dim3(L / 256, L / 256, NB), 512, 0, stream>>>(
            pB + boff, tQ + boff, S, nullptr, (int)L, (int)L, (int)H,
            L * H, L * H, L * L);
        // softmax rows -> P fp16
        softmax_p<<<NB * L, 256, 0, stream>>>(S, P);
        // G3: aV[p,h] = P[p,:] . qBt[h,:]   (256x128-tile 4-phase, K=2048)
        gemm_bt3<f16, false, false><<<dim3(H / 128, L / 256, NB), 512, 0, stream>>>(
            P, qBt + (long)c * NB * H * L, aV + boff, nullptr, (int)L, (int)H, (int)L,
            L * L, H * L, L * H);
    }

    // G4: out = relu(aV . Wb^T + bias)  (fp32 out, 256-tile 8-phase)
    gemm_bt2<float, false, true><<<dim3(H / 256, (Bc * L) / 256, 1), 512, 0, stream>>>(
        aV, Wb, out, bias, (int)(Bc * L), (int)H, (int)H, 0, 0, 0);
}